// Round 4
// baseline (334.009 us; speedup 1.0000x reference)
//
#include <hip/hip_runtime.h>

// AttentionGate: out[b,cf,v] = x[b,cf,v] * sigmoid(Wpsi · relu(Wg·g[b,:,v] + Wx·x[b,:,v]))
// B=2, CF=CG=64, CI=32, SPAT=64^3. fp32.
//
// R3: deepen memory-level parallelism + packed fp32 math.
// R2 counters (113us, BW 37%, VALU 30%, VGPR 52) showed shallow pipelining:
// 4 loads in flight then a 256-instr FMA block with none outstanding.
// Now: explicit 8-channel load batches (16 loads in flight/wave), and v2f
// vector arithmetic so the compiler emits v_pk_fma_f32 (halves VALU issue).

#define SPAT 262144        // 64*64*64
#define NVOX 524288        // B * SPAT
#define CIN  64
#define COUT 32
#define S2   (SPAT / 2)    // vec2 elements per (b,c) plane = 2^17
#define UC   8             // channel unroll (load batch depth)

typedef float v2f __attribute__((ext_vector_type(2)));

__global__ __launch_bounds__(256) void transpose_w(const float* __restrict__ Wg,
                                                   const float* __restrict__ Wx,
                                                   float* __restrict__ Wcat) {
    int idx = blockIdx.x * 256 + threadIdx.x;   // 0..4095
    int c = idx >> 6;
    int o = idx & 63;
    float v = (o < 32) ? Wg[o * CIN + c] : Wx[(o - 32) * CIN + c];
    Wcat[c * 64 + o] = v;
}

__global__ __launch_bounds__(256, 4) void gate_main(const v2f* __restrict__ x,
                                                    const v2f* __restrict__ g,
                                                    const float* __restrict__ Wcat,
                                                    const float* __restrict__ Wpsi,
                                                    v2f* __restrict__ out) {
    int p = blockIdx.x * 256 + threadIdx.x;     // pair index 0..262143
    int b = p >> 17;                            // S2 = 2^17
    int s = p & (S2 - 1);

    const v2f* __restrict__ xp = x + (size_t)b * CIN * S2 + s;
    const v2f* __restrict__ gp = g + (size_t)b * CIN * S2 + s;

    v2f acc[COUT];
#pragma unroll
    for (int o = 0; o < COUT; ++o) acc[o] = (v2f)(0.0f);

    for (int cb = 0; cb < CIN; cb += UC) {
        v2f gv[UC], xv[UC];
#pragma unroll
        for (int u = 0; u < UC; ++u) {
            gv[u] = __builtin_nontemporal_load(gp + (size_t)(cb + u) * S2);
            xv[u] = xp[(size_t)(cb + u) * S2];
        }
#pragma unroll
        for (int u = 0; u < UC; ++u) {
            const float* w = Wcat + (cb + u) * 64;   // wave-uniform -> s_load
#pragma unroll
            for (int o = 0; o < COUT; ++o) {
                // vector expr -> v_pk_fma_f32 (fp-contract fuses mul+add)
                acc[o] = gv[u] * w[o] + (xv[u] * w[32 + o] + acc[o]);
            }
        }
    }

    float px = 0.0f, py = 0.0f;
#pragma unroll
    for (int o = 0; o < COUT; ++o) {
        float wp = Wpsi[o];
        px = fmaf(wp, fmaxf(acc[o].x, 0.0f), px);
        py = fmaf(wp, fmaxf(acc[o].y, 0.0f), py);
    }
    v2f psi2;
    psi2.x = 1.0f / (1.0f + __expf(-px));
    psi2.y = 1.0f / (1.0f + __expf(-py));

    v2f* __restrict__ op = out + (size_t)b * CIN * S2 + s;
    for (int cb = 0; cb < CIN; cb += UC) {
        v2f xv[UC];
#pragma unroll
        for (int u = 0; u < UC; ++u)
            xv[u] = xp[(size_t)(cb + u) * S2];       // L1/L2-warm re-read
#pragma unroll
        for (int u = 0; u < UC; ++u)
            __builtin_nontemporal_store(xv[u] * psi2, op + (size_t)(cb + u) * S2);
    }
}

extern "C" void kernel_launch(void* const* d_in, const int* in_sizes, int n_in,
                              void* d_out, int out_size, void* d_ws, size_t ws_size,
                              hipStream_t stream) {
    const float* x    = (const float*)d_in[0];
    const float* g    = (const float*)d_in[1];
    const float* Wg   = (const float*)d_in[2];
    const float* Wx   = (const float*)d_in[3];
    const float* Wpsi = (const float*)d_in[4];
    float* out  = (float*)d_out;
    float* Wcat = (float*)d_ws;                 // 64*64 floats = 16 KB scratch

    transpose_w<<<16, 256, 0, stream>>>(Wg, Wx, Wcat);
    gate_main<<<NVOX / 2 / 256, 256, 0, stream>>>((const v2f*)x, (const v2f*)g,
                                                  Wcat, Wpsi, (v2f*)out);
}